// Round 7
// baseline (542.002 us; speedup 1.0000x reference)
//
#include <hip/hip_runtime.h>

typedef __bf16 bf16_t;
typedef __bf16 v8bf __attribute__((ext_vector_type(8)));
typedef __bf16 v4bf __attribute__((ext_vector_type(4)));
typedef float  v4f  __attribute__((ext_vector_type(4)));

#define D_MODEL 1024
#define NHEAD   16
#define DHEAD   64
#define SEQ     2048
#define BATCH   4
#define ROWS    (BATCH*SEQ)   // 8192

// async global->LDS, 16B per lane; LDS dest = wave-uniform base + lane*16
#define GLD16(g, l) __builtin_amdgcn_global_load_lds( \
    (const __attribute__((address_space(1))) void*)(g), \
    (__attribute__((address_space(3))) void*)(l), 16, 0, 0)

// ---------------------------------------------------------------- converts
__global__ __launch_bounds__(256) void k_f32_to_bf16(const float* __restrict__ src,
                                                     bf16_t* __restrict__ dst, int n4) {
    int i = blockIdx.x * 256 + threadIdx.x;
    if (i >= n4) return;
    float4 f = ((const float4*)src)[i];
    v4bf o;
    o[0] = (bf16_t)f.x; o[1] = (bf16_t)f.y; o[2] = (bf16_t)f.z; o[3] = (bf16_t)f.w;
    ((v4bf*)dst)[i] = o;
}

__global__ __launch_bounds__(256) void k_pack_bias(const float* __restrict__ a,
                                                   const float* __restrict__ b,
                                                   const float* __restrict__ c,
                                                   float* __restrict__ dst) {
    int i = blockIdx.x * 256 + threadIdx.x;
    if (i < 1024) { dst[i] = a[i]; dst[i + 1024] = b[i]; dst[i + 2048] = c[i]; }
}

// ---------------------------------------------------------------- GEMM  C = A * B^T (+bias) (+resid)
// global_load_lds staging, double-buffered LDS, ONE barrier per K-iter.
// Unpadded 128x32 tiles, XOR swizzle (row r: logical chunk c at phys c^((r>>1)&3)).
__global__ __launch_bounds__(256, 3) void k_gemm_bt(
    const bf16_t* __restrict__ A, const bf16_t* __restrict__ Bm,
    const float* __restrict__ bias, const float* __restrict__ resid,
    bf16_t* __restrict__ Cb, float* __restrict__ Cf,
    int M, int N, int K, int qcols, float qmul)
{
    __shared__ bf16_t As[2][128 * 32];
    __shared__ bf16_t Bs[2][128 * 32];

    int nTile = N >> 7;
    int m0 = (blockIdx.x / nTile) << 7;
    int n0 = (blockIdx.x % nTile) << 7;
    int t = threadIdx.x;
    int w = t >> 6, lane = t & 63, quad = lane >> 4, ln = lane & 15;
    int wm = (w >> 1) << 6, wn = (w & 1) << 6;

    int srow = lane >> 2;                               // 0..15
    int scol = ((lane & 3) ^ ((lane >> 3) & 3)) << 3;   // swizzled logical chunk *8
    const bf16_t* Ag0 = A  + (size_t)(m0 + w * 16 +      srow) * K + scol;
    const bf16_t* Ag1 = A  + (size_t)(m0 + w * 16 + 64 + srow) * K + scol;
    const bf16_t* Bg0 = Bm + (size_t)(n0 + w * 16 +      srow) * K + scol;
    const bf16_t* Bg1 = Bm + (size_t)(n0 + w * 16 + 64 + srow) * K + scol;
    int lo0 = (w * 16) * 32, lo1 = (w * 16 + 64) * 32;

    v4f acc[4][4];
#pragma unroll
    for (int i = 0; i < 4; i++)
#pragma unroll
        for (int j = 0; j < 4; j++) acc[i][j] = (v4f){0.f, 0.f, 0.f, 0.f};

    // prologue: tile 0 -> buf 0
    GLD16(Ag0, &As[0][lo0]);
    GLD16(Ag1, &As[0][lo1]);
    GLD16(Bg0, &Bs[0][lo0]);
    GLD16(Bg1, &Bs[0][lo1]);

    int sw = (ln >> 1) & 3;   // read-side swizzle
    int buf = 0;
    for (int k0 = 0; k0 < K; k0 += 32, buf ^= 1) {
        __syncthreads();   // vmcnt(0) drain covers tile-k0 loads (in flight since k0-32)
        if (k0 + 32 < K) {
            GLD16(Ag0 + k0 + 32, &As[buf ^ 1][lo0]);
            GLD16(Ag1 + k0 + 32, &As[buf ^ 1][lo1]);
            GLD16(Bg0 + k0 + 32, &Bs[buf ^ 1][lo0]);
            GLD16(Bg1 + k0 + 32, &Bs[buf ^ 1][lo1]);
        }
        v8bf af[4], bfr[4];
#pragma unroll
        for (int mt = 0; mt < 4; mt++)
            af[mt] = *(const v8bf*)&As[buf][(wm + mt * 16 + ln) * 32 + ((quad ^ sw) << 3)];
#pragma unroll
        for (int nt = 0; nt < 4; nt++)
            bfr[nt] = *(const v8bf*)&Bs[buf][(wn + nt * 16 + ln) * 32 + ((quad ^ sw) << 3)];
#pragma unroll
        for (int mt = 0; mt < 4; mt++)
#pragma unroll
            for (int nt = 0; nt < 4; nt++)
                acc[mt][nt] = __builtin_amdgcn_mfma_f32_16x16x32_bf16(af[mt], bfr[nt], acc[mt][nt], 0, 0, 0);
    }

#pragma unroll
    for (int mt = 0; mt < 4; mt++) {
#pragma unroll
        for (int r = 0; r < 4; r++) {
            int row = m0 + wm + mt * 16 + quad * 4 + r;
#pragma unroll
            for (int nt = 0; nt < 4; nt++) {
                int col = n0 + wn + nt * 16 + ln;
                float v = acc[mt][nt][r] + bias[col];
                if (Cf) Cf[(size_t)row * N + col] = v + resid[(size_t)row * N + col];
                else {
                    if (col < qcols) v *= qmul;
                    Cb[(size_t)row * N + col] = (bf16_t)v;
                }
            }
        }
    }
}

// ---------------------------------------------------------------- V transpose: qkv V-cols -> Vt[bh][d][s]
__global__ __launch_bounds__(256) void k_transpose_v(const bf16_t* __restrict__ qkv,
                                                     bf16_t* __restrict__ vt) {
    __shared__ bf16_t tile[64 * 72];
    int bid = blockIdx.x;
    int st = bid & 31, bh = bid >> 5, b = bh >> 4, h = bh & 15;
    int t = threadIdx.x;
    const bf16_t* src = qkv + (size_t)(b * SEQ + st * 64) * 3072 + 2048 + h * 64;
#pragma unroll
    for (int i = 0; i < 2; i++) {
        int c = t + i * 256, row = c >> 3, c8 = (c & 7) << 3;
        *(uint4*)&tile[row * 72 + c8] = *(const uint4*)(src + (size_t)row * 3072 + c8);
    }
    __syncthreads();
    bf16_t* dst = vt + (size_t)bh * DHEAD * SEQ + st * 64;
#pragma unroll
    for (int i = 0; i < 2; i++) {
        int c = t + i * 256, d = c >> 3, s8 = (c & 7) << 3;
        v8bf o;
#pragma unroll
        for (int j = 0; j < 8; j++) o[j] = tile[(s8 + j) * 72 + d];
        *(v8bf*)(dst + (size_t)d * SEQ + s8) = o;
    }
}

// ---------------------------------------------------------------- attention
// grid: B*H*(S/128) = 1024 blocks, 256 thr; wave owns 32 q-rows (2 q-sets).
// LDS EXACTLY 40 KB (Ks 2x8K + Vs 2x8K + P 8K) -> 4 blocks/CU, and grid
// 1024 = 4 x 256 CUs tiles the machine with ZERO TAIL (round-6: 41.4 KB ->
// 3 blocks -> rounds of 768+256 -> avg 2 blocks/CU = the 27% occupancy).
// K/V: double-buffered unpadded 64x64 tiles via global_load_lds, XOR swizzle
// chunk^(row&7), one barrier/iter. P: per-wave 16x64, XOR chunk swizzle
// (elem (m,k) at m*64 + ((chunk(k)^key(m))<<3) + (k&7), key(m)=(m+2*(m>>3))&7)
// -> conflict-free writes, even 8-cyc b128 reads, zero padding.
// qs chains interleaved: exp2+write qs1 overlaps PV-qs0 MFMA execution.
__global__ __launch_bounds__(256, 4) void k_attn(const bf16_t* __restrict__ qkv,
                                                 const bf16_t* __restrict__ vt,
                                                 bf16_t* __restrict__ attn) {
    __shared__ bf16_t Ks[2][64 * 64];
    __shared__ bf16_t Vs[2][64 * 64];
    __shared__ bf16_t Pl[4][16 * 64];

    int bid = blockIdx.x;
    int qt = bid & 15, bh = bid >> 4, b = bh >> 4, h = bh & 15;
    int t = threadIdx.x, w = t >> 6, lane = t & 63, quad = lane >> 4, ln = lane & 15;
    int q0 = qt * 128 + w * 32;

    v8bf qf[2][2];
#pragma unroll
    for (int qs = 0; qs < 2; qs++) {
        const bf16_t* Qp = qkv + (size_t)(b * SEQ + q0 + qs * 16 + ln) * 3072 + h * 64 + quad * 8;
        qf[qs][0] = *(const v8bf*)Qp;
        qf[qs][1] = *(const v8bf*)(Qp + 32);
    }

    // staging addresses: wave w instr i covers rows (w+4i)*8 .. +7
    int srow = lane >> 3;                        // 0..7
    int scol = ((lane & 7) ^ (lane >> 3)) << 3;  // swizzled logical chunk *8
    const bf16_t* Kg0 = qkv + (size_t)(b * SEQ + w * 8 +      srow) * 3072 + 1024 + h * 64 + scol;
    const bf16_t* Kg1 = qkv + (size_t)(b * SEQ + w * 8 + 32 + srow) * 3072 + 1024 + h * 64 + scol;
    const bf16_t* Vg0 = vt + (size_t)bh * DHEAD * SEQ + (size_t)(w * 8 +      srow) * SEQ + scol;
    const bf16_t* Vg1 = vt + (size_t)bh * DHEAD * SEQ + (size_t)(w * 8 + 32 + srow) * SEQ + scol;
    int ko0 = (w * 8) * 64, ko1 = (w * 8 + 32) * 64;

    bf16_t* Pw = &Pl[w][0];
    int sw = ln & 7;                       // read-side swizzle for K/V
    int e = ln & 7, hi = ln >> 3;          // P-write helpers
    int kq = quad * 4 + 2 * (quad >> 1);   // P-write key base: key=(kq+r)&7
    int kr = (ln + 2 * hi) & 7;            // P-read key

    v4f o[2][4];
#pragma unroll
    for (int qs = 0; qs < 2; qs++)
#pragma unroll
        for (int d = 0; d < 4; d++) o[qs][d] = (v4f){0.f, 0.f, 0.f, 0.f};
    float lsum[2][4] = {{0.f,0.f,0.f,0.f},{0.f,0.f,0.f,0.f}};

    // prologue: tile 0 -> buf 0
    GLD16(Kg0, &Ks[0][ko0]);
    GLD16(Kg1, &Ks[0][ko1]);
    GLD16(Vg0, &Vs[0][ko0]);
    GLD16(Vg1, &Vs[0][ko1]);

    int buf = 0;
    for (int kt = 0; kt < SEQ; kt += 64, buf ^= 1) {
        __syncthreads();   // vmcnt(0) drain covers tile-kt loads (issued last iter)
        if (kt + 64 < SEQ) {
            GLD16(Kg0 + (size_t)(kt + 64) * 3072, &Ks[buf ^ 1][ko0]);
            GLD16(Kg1 + (size_t)(kt + 64) * 3072, &Ks[buf ^ 1][ko1]);
            GLD16(Vg0 + kt + 64, &Vs[buf ^ 1][ko0]);
            GLD16(Vg1 + kt + 64, &Vs[buf ^ 1][ko1]);
        }

        // QK^T for both q-sets
        v4f s0[4], s1[4];
#pragma unroll
        for (int nt = 0; nt < 4; nt++) {
            v8bf kf0 = *(const v8bf*)&Ks[buf][(nt * 16 + ln) * 64 + ((quad ^ sw) << 3)];
            v8bf kf1 = *(const v8bf*)&Ks[buf][(nt * 16 + ln) * 64 + (((quad + 4) ^ sw) << 3)];
            s0[nt] = (v4f){0.f, 0.f, 0.f, 0.f};
            s1[nt] = (v4f){0.f, 0.f, 0.f, 0.f};
            s0[nt] = __builtin_amdgcn_mfma_f32_16x16x32_bf16(qf[0][0], kf0, s0[nt], 0, 0, 0);
            s0[nt] = __builtin_amdgcn_mfma_f32_16x16x32_bf16(qf[0][1], kf1, s0[nt], 0, 0, 0);
            s1[nt] = __builtin_amdgcn_mfma_f32_16x16x32_bf16(qf[1][0], kf0, s1[nt], 0, 0, 0);
            s1[nt] = __builtin_amdgcn_mfma_f32_16x16x32_bf16(qf[1][1], kf1, s1[nt], 0, 0, 0);
        }

        // V fragments (shared by both q-sets)
        v8bf vf[8];
#pragma unroll
        for (int d = 0; d < 4; d++) {
            vf[d * 2]     = *(const v8bf*)&Vs[buf][(d * 16 + ln) * 64 + ((quad ^ sw) << 3)];
            vf[d * 2 + 1] = *(const v8bf*)&Vs[buf][(d * 16 + ln) * 64 + (((quad + 4) ^ sw) << 3)];
        }

        // qs0: exp2 + swizzled P store + denom
#pragma unroll
        for (int r = 0; r < 4; r++) {
            float p0 = __builtin_amdgcn_exp2f(s0[0][r]);
            float p1 = __builtin_amdgcn_exp2f(s0[1][r]);
            float p2 = __builtin_amdgcn_exp2f(s0[2][r]);
            float p3 = __builtin_amdgcn_exp2f(s0[3][r]);
            int kw = (kq + r) & 7;
            bf16_t* pr = &Pw[(quad * 4 + r) * 64 + e];
            pr[((0 + hi) ^ kw) << 3] = (bf16_t)p0;
            pr[((2 + hi) ^ kw) << 3] = (bf16_t)p1;
            pr[((4 + hi) ^ kw) << 3] = (bf16_t)p2;
            pr[((6 + hi) ^ kw) << 3] = (bf16_t)p3;
            lsum[0][r] += (p0 + p1) + (p2 + p3);
        }
        // PV qs0 (MFMAs execute async under qs1's exp2 below)
#pragma unroll
        for (int tk = 0; tk < 2; tk++) {
            v8bf pf = *(const v8bf*)&Pw[ln * 64 + (((tk * 4 + quad) ^ kr) << 3)];
#pragma unroll
            for (int d = 0; d < 4; d++)
                o[0][d] = __builtin_amdgcn_mfma_f32_16x16x32_bf16(pf, vf[tk + d * 2], o[0][d], 0, 0, 0);
        }
        // qs1: exp2 + P store (in-order DS queue: these writes follow qs0's reads)
#pragma unroll
        for (int r = 0; r < 4; r++) {
            float p0 = __builtin_amdgcn_exp2f(s1[0][r]);
            float p1 = __builtin_amdgcn_exp2f(s1[1][r]);
            float p2 = __builtin_amdgcn_exp2f(s1[2][r]);
            float p3 = __builtin_amdgcn_exp2f(s1[3][r]);
            int kw = (kq + r) & 7;
            bf16_t* pr = &Pw[(quad * 4 + r) * 64 + e];
            pr[((0 + hi) ^ kw) << 3] = (bf16_t)p0;
            pr[((2 + hi) ^ kw) << 3] = (bf16_t)p1;
            pr[((4 + hi) ^ kw) << 3] = (bf16_t)p2;
            pr[((6 + hi) ^ kw) << 3] = (bf16_t)p3;
            lsum[1][r] += (p0 + p1) + (p2 + p3);
        }
#pragma unroll
        for (int tk = 0; tk < 2; tk++) {
            v8bf pf = *(const v8bf*)&Pw[ln * 64 + (((tk * 4 + quad) ^ kr) << 3)];
#pragma unroll
            for (int d = 0; d < 4; d++)
                o[1][d] = __builtin_amdgcn_mfma_f32_16x16x32_bf16(pf, vf[tk + d * 2], o[1][d], 0, 0, 0);
        }
    }

#pragma unroll
    for (int qs = 0; qs < 2; qs++)
#pragma unroll
        for (int r = 0; r < 4; r++) {
#pragma unroll
            for (int off = 1; off < 16; off <<= 1) lsum[qs][r] += __shfl_xor(lsum[qs][r], off);
        }

#pragma unroll
    for (int qs = 0; qs < 2; qs++) {
        int rowg = b * SEQ + q0 + qs * 16;
#pragma unroll
        for (int r = 0; r < 4; r++) {
            float inv = 1.f / lsum[qs][r];
#pragma unroll
            for (int d = 0; d < 4; d++)
                attn[(size_t)(rowg + quad * 4 + r) * D_MODEL + h * 64 + d * 16 + ln] =
                    (bf16_t)(o[qs][d][r] * inv);
        }
    }
}

// ---------------------------------------------------------------- LayerNorm (one row / block)
__global__ __launch_bounds__(256) void k_layernorm(const float* __restrict__ y,
                                                   const float* __restrict__ g,
                                                   const float* __restrict__ beta,
                                                   float* __restrict__ out) {
    __shared__ float rs[4], rq[4];
    int row = blockIdx.x, t = threadIdx.x;
    int w = t >> 6, lane = t & 63;
    float4 v = ((const float4*)(y + (size_t)row * D_MODEL))[t];
    float s = v.x + v.y + v.z + v.w;
    float q = v.x * v.x + v.y * v.y + v.z * v.z + v.w * v.w;
#pragma unroll
    for (int off = 1; off < 64; off <<= 1) {
        s += __shfl_xor(s, off);
        q += __shfl_xor(q, off);
    }
    if (lane == 0) { rs[w] = s; rq[w] = q; }
    __syncthreads();
    s = rs[0] + rs[1] + rs[2] + rs[3];
    q = rq[0] + rq[1] + rq[2] + rq[3];
    float mu = s * (1.f / D_MODEL);
    float var = q * (1.f / D_MODEL) - mu * mu;
    float rstd = rsqrtf(var + 1e-5f);
    float4 gg = ((const float4*)g)[t];
    float4 bb = ((const float4*)beta)[t];
    float4 o;
    o.x = (v.x - mu) * rstd * gg.x + bb.x;
    o.y = (v.y - mu) * rstd * gg.y + bb.y;
    o.z = (v.z - mu) * rstd * gg.z + bb.z;
    o.w = (v.w - mu) * rstd * gg.w + bb.w;
    ((float4*)(out + (size_t)row * D_MODEL))[t] = o;
}

// ---------------------------------------------------------------- launch
extern "C" void kernel_launch(void* const* d_in, const int* in_sizes, int n_in,
                              void* d_out, int out_size, void* d_ws, size_t ws_size,
                              hipStream_t stream) {
    const float* batch = (const float*)d_in[0];
    const float* wq = (const float*)d_in[1];
    const float* bq = (const float*)d_in[2];
    const float* wk = (const float*)d_in[3];
    const float* bk = (const float*)d_in[4];
    const float* wv = (const float*)d_in[5];
    const float* bv = (const float*)d_in[6];
    const float* wo = (const float*)d_in[7];
    const float* bo = (const float*)d_in[8];
    const float* ln_g = (const float*)d_in[9];
    const float* ln_b = (const float*)d_in[10];
    float* out = (float*)d_out;

    char* ws = (char*)d_ws;
    size_t offXb   = 0;                                          // bf16 X (later Vt)
    size_t offWqkv = offXb + (size_t)ROWS * D_MODEL * 2;
    size_t offWo   = offWqkv + (size_t)3072 * 1024 * 2;
    size_t offBias = offWo + (size_t)1024 * 1024 * 2;
    size_t offQKV  = offBias + 3072 * 4;                         // bf16 qkv (later fp32 y)
    size_t offAttn = offQKV + (size_t)ROWS * 3072 * 2;
    size_t total   = offAttn + (size_t)ROWS * D_MODEL * 2;       // = 92,286,976
    if (ws_size < total) return;

    bf16_t* Xb   = (bf16_t*)(ws + offXb);
    bf16_t* Vt   = (bf16_t*)(ws + offXb);
    bf16_t* Wqkv = (bf16_t*)(ws + offWqkv);
    bf16_t* Wob  = (bf16_t*)(ws + offWo);
    float*  bqkv = (float*)(ws + offBias);
    bf16_t* qkv  = (bf16_t*)(ws + offQKV);
    float*  y    = (float*)(ws + offQKV);
    bf16_t* attn = (bf16_t*)(ws + offAttn);

    const float SC = 0.125f * 1.44269504088896f;  // 1/sqrt(64) * log2(e), folded into Q

    k_f32_to_bf16<<<8192, 256, 0, stream>>>(batch, Xb, 2097152);
    k_f32_to_bf16<<<1024, 256, 0, stream>>>(wq, Wqkv, 262144);
    k_f32_to_bf16<<<1024, 256, 0, stream>>>(wk, Wqkv + 1048576, 262144);
    k_f32_to_bf16<<<1024, 256, 0, stream>>>(wv, Wqkv + 2097152, 262144);
    k_f32_to_bf16<<<1024, 256, 0, stream>>>(wo, Wob, 262144);
    k_pack_bias<<<4, 256, 0, stream>>>(bq, bk, bv, bqkv);

    k_gemm_bt<<<64 * 24, 256, 0, stream>>>(Xb, Wqkv, bqkv, nullptr, qkv, nullptr,
                                           8192, 3072, 1024, 1024, SC);
    k_transpose_v<<<2048, 256, 0, stream>>>(qkv, Vt);
    k_attn<<<1024, 256, 0, stream>>>(qkv, Vt, attn);
    k_gemm_bt<<<64 * 8, 256, 0, stream>>>(attn, Wob, bo, batch, nullptr, y,
                                          8192, 1024, 1024, 0, 1.0f);
    k_layernorm<<<8192, 256, 0, stream>>>(y, ln_g, ln_b, out);
}

// Round 8
// 357.162 us; speedup vs baseline: 1.5175x; 1.5175x over previous
//
#include <hip/hip_runtime.h>

typedef __bf16 bf16_t;
typedef __bf16 v8bf __attribute__((ext_vector_type(8)));
typedef __bf16 v4bf __attribute__((ext_vector_type(4)));
typedef float  v4f  __attribute__((ext_vector_type(4)));

#define D_MODEL 1024
#define NHEAD   16
#define DHEAD   64
#define SEQ     2048
#define BATCH   4
#define ROWS    (BATCH*SEQ)   // 8192

// async global->LDS, 16B per lane; LDS dest = wave-uniform base + lane*16
#define GLD16(g, l) __builtin_amdgcn_global_load_lds( \
    (const __attribute__((address_space(1))) void*)(g), \
    (__attribute__((address_space(3))) void*)(l), 16, 0, 0)

// ---------------------------------------------------------------- converts
__global__ __launch_bounds__(256) void k_f32_to_bf16(const float* __restrict__ src,
                                                     bf16_t* __restrict__ dst, int n4) {
    int i = blockIdx.x * 256 + threadIdx.x;
    if (i >= n4) return;
    float4 f = ((const float4*)src)[i];
    v4bf o;
    o[0] = (bf16_t)f.x; o[1] = (bf16_t)f.y; o[2] = (bf16_t)f.z; o[3] = (bf16_t)f.w;
    ((v4bf*)dst)[i] = o;
}

__global__ __launch_bounds__(256) void k_pack_bias(const float* __restrict__ a,
                                                   const float* __restrict__ b,
                                                   const float* __restrict__ c,
                                                   float* __restrict__ dst) {
    int i = blockIdx.x * 256 + threadIdx.x;
    if (i < 1024) { dst[i] = a[i]; dst[i + 1024] = b[i]; dst[i + 2048] = c[i]; }
}

// ---------------------------------------------------------------- GEMM  C = A * B^T (+bias) (+resid)
// global_load_lds staging, double-buffered LDS, ONE barrier per K-iter.
// Unpadded 128x32 tiles, XOR swizzle (row r: logical chunk c at phys c^((r>>1)&3)).
__global__ __launch_bounds__(256, 3) void k_gemm_bt(
    const bf16_t* __restrict__ A, const bf16_t* __restrict__ Bm,
    const float* __restrict__ bias, const float* __restrict__ resid,
    bf16_t* __restrict__ Cb, float* __restrict__ Cf,
    int M, int N, int K, int qcols, float qmul)
{
    __shared__ bf16_t As[2][128 * 32];
    __shared__ bf16_t Bs[2][128 * 32];

    int nTile = N >> 7;
    int m0 = (blockIdx.x / nTile) << 7;
    int n0 = (blockIdx.x % nTile) << 7;
    int t = threadIdx.x;
    int w = t >> 6, lane = t & 63, quad = lane >> 4, ln = lane & 15;
    int wm = (w >> 1) << 6, wn = (w & 1) << 6;

    int srow = lane >> 2;                               // 0..15
    int scol = ((lane & 3) ^ ((lane >> 3) & 3)) << 3;   // swizzled logical chunk *8
    const bf16_t* Ag0 = A  + (size_t)(m0 + w * 16 +      srow) * K + scol;
    const bf16_t* Ag1 = A  + (size_t)(m0 + w * 16 + 64 + srow) * K + scol;
    const bf16_t* Bg0 = Bm + (size_t)(n0 + w * 16 +      srow) * K + scol;
    const bf16_t* Bg1 = Bm + (size_t)(n0 + w * 16 + 64 + srow) * K + scol;
    int lo0 = (w * 16) * 32, lo1 = (w * 16 + 64) * 32;

    v4f acc[4][4];
#pragma unroll
    for (int i = 0; i < 4; i++)
#pragma unroll
        for (int j = 0; j < 4; j++) acc[i][j] = (v4f){0.f, 0.f, 0.f, 0.f};

    // prologue: tile 0 -> buf 0
    GLD16(Ag0, &As[0][lo0]);
    GLD16(Ag1, &As[0][lo1]);
    GLD16(Bg0, &Bs[0][lo0]);
    GLD16(Bg1, &Bs[0][lo1]);

    int sw = (ln >> 1) & 3;   // read-side swizzle
    int buf = 0;
    for (int k0 = 0; k0 < K; k0 += 32, buf ^= 1) {
        __syncthreads();   // vmcnt(0) drain covers tile-k0 loads (in flight since k0-32)
        if (k0 + 32 < K) {
            GLD16(Ag0 + k0 + 32, &As[buf ^ 1][lo0]);
            GLD16(Ag1 + k0 + 32, &As[buf ^ 1][lo1]);
            GLD16(Bg0 + k0 + 32, &Bs[buf ^ 1][lo0]);
            GLD16(Bg1 + k0 + 32, &Bs[buf ^ 1][lo1]);
        }
        v8bf af[4], bfr[4];
#pragma unroll
        for (int mt = 0; mt < 4; mt++)
            af[mt] = *(const v8bf*)&As[buf][(wm + mt * 16 + ln) * 32 + ((quad ^ sw) << 3)];
#pragma unroll
        for (int nt = 0; nt < 4; nt++)
            bfr[nt] = *(const v8bf*)&Bs[buf][(wn + nt * 16 + ln) * 32 + ((quad ^ sw) << 3)];
#pragma unroll
        for (int mt = 0; mt < 4; mt++)
#pragma unroll
            for (int nt = 0; nt < 4; nt++)
                acc[mt][nt] = __builtin_amdgcn_mfma_f32_16x16x32_bf16(af[mt], bfr[nt], acc[mt][nt], 0, 0, 0);
    }

#pragma unroll
    for (int mt = 0; mt < 4; mt++) {
#pragma unroll
        for (int r = 0; r < 4; r++) {
            int row = m0 + wm + mt * 16 + quad * 4 + r;
#pragma unroll
            for (int nt = 0; nt < 4; nt++) {
                int col = n0 + wn + nt * 16 + ln;
                float v = acc[mt][nt][r] + bias[col];
                if (Cf) Cf[(size_t)row * N + col] = v + resid[(size_t)row * N + col];
                else {
                    if (col < qcols) v *= qmul;
                    Cb[(size_t)row * N + col] = (bf16_t)v;
                }
            }
        }
    }
}

// ---------------------------------------------------------------- V transpose: qkv V-cols -> Vt[bh][d][s]
__global__ __launch_bounds__(256) void k_transpose_v(const bf16_t* __restrict__ qkv,
                                                     bf16_t* __restrict__ vt) {
    __shared__ bf16_t tile[64 * 72];
    int bid = blockIdx.x;
    int st = bid & 31, bh = bid >> 5, b = bh >> 4, h = bh & 15;
    int t = threadIdx.x;
    const bf16_t* src = qkv + (size_t)(b * SEQ + st * 64) * 3072 + 2048 + h * 64;
#pragma unroll
    for (int i = 0; i < 2; i++) {
        int c = t + i * 256, row = c >> 3, c8 = (c & 7) << 3;
        *(uint4*)&tile[row * 72 + c8] = *(const uint4*)(src + (size_t)row * 3072 + c8);
    }
    __syncthreads();
    bf16_t* dst = vt + (size_t)bh * DHEAD * SEQ + st * 64;
#pragma unroll
    for (int i = 0; i < 2; i++) {
        int c = t + i * 256, d = c >> 3, s8 = (c & 7) << 3;
        v8bf o;
#pragma unroll
        for (int j = 0; j < 8; j++) o[j] = tile[(s8 + j) * 72 + d];
        *(v8bf*)(dst + (size_t)d * SEQ + s8) = o;
    }
}

// ---------------------------------------------------------------- attention
// grid: B*H*(S/128) = 1024 blocks, 256 thr; wave owns 32 q-rows (2 q-sets).
// LDS EXACTLY 40 KB (Ks 2x8K + Vs 2x8K + P 8K) -> 4 blocks/CU, grid 1024 =
// 4 x 256 CUs, zero tail. launch_bounds (256,3): round 7 showed (256,4)
// hard-caps VGPR at 64 -> massive scratch spills (WRITE_SIZE 16->556 MB);
// natural allocation (~76) already fits the 4-waves/EU budget of 128.
// K/V: double-buffered unpadded 64x64 tiles via global_load_lds, XOR swizzle
// chunk^(row&7), one barrier/iter. P: per-wave 16x64, XOR chunk swizzle
// (elem (m,k) at m*64 + ((chunk(k)^key(m))<<3) + (k&7), key(m)=(m+2*(m>>3))&7).
__global__ __launch_bounds__(256, 3) void k_attn(const bf16_t* __restrict__ qkv,
                                                 const bf16_t* __restrict__ vt,
                                                 bf16_t* __restrict__ attn) {
    __shared__ bf16_t Ks[2][64 * 64];
    __shared__ bf16_t Vs[2][64 * 64];
    __shared__ bf16_t Pl[4][16 * 64];

    int bid = blockIdx.x;
    int qt = bid & 15, bh = bid >> 4, b = bh >> 4, h = bh & 15;
    int t = threadIdx.x, w = t >> 6, lane = t & 63, quad = lane >> 4, ln = lane & 15;
    int q0 = qt * 128 + w * 32;

    v8bf qf[2][2];
#pragma unroll
    for (int qs = 0; qs < 2; qs++) {
        const bf16_t* Qp = qkv + (size_t)(b * SEQ + q0 + qs * 16 + ln) * 3072 + h * 64 + quad * 8;
        qf[qs][0] = *(const v8bf*)Qp;
        qf[qs][1] = *(const v8bf*)(Qp + 32);
    }

    // staging addresses: wave w instr i covers rows (w+4i)*8 .. +7
    int srow = lane >> 3;                        // 0..7
    int scol = ((lane & 7) ^ (lane >> 3)) << 3;  // swizzled logical chunk *8
    const bf16_t* Kg0 = qkv + (size_t)(b * SEQ + w * 8 +      srow) * 3072 + 1024 + h * 64 + scol;
    const bf16_t* Kg1 = qkv + (size_t)(b * SEQ + w * 8 + 32 + srow) * 3072 + 1024 + h * 64 + scol;
    const bf16_t* Vg0 = vt + (size_t)bh * DHEAD * SEQ + (size_t)(w * 8 +      srow) * SEQ + scol;
    const bf16_t* Vg1 = vt + (size_t)bh * DHEAD * SEQ + (size_t)(w * 8 + 32 + srow) * SEQ + scol;
    int ko0 = (w * 8) * 64, ko1 = (w * 8 + 32) * 64;

    bf16_t* Pw = &Pl[w][0];
    int sw = ln & 7;                       // read-side swizzle for K/V
    int e = ln & 7, hi = ln >> 3;          // P-write helpers
    int kq = quad * 4 + 2 * (quad >> 1);   // P-write key base: key=(kq+r)&7
    int kr = (ln + 2 * hi) & 7;            // P-read key

    v4f o[2][4];
#pragma unroll
    for (int qs = 0; qs < 2; qs++)
#pragma unroll
        for (int d = 0; d < 4; d++) o[qs][d] = (v4f){0.f, 0.f, 0.f, 0.f};
    float lsum[2][4] = {{0.f,0.f,0.f,0.f},{0.f,0.f,0.f,0.f}};

    // prologue: tile 0 -> buf 0
    GLD16(Kg0, &Ks[0][ko0]);
    GLD16(Kg1, &Ks[0][ko1]);
    GLD16(Vg0, &Vs[0][ko0]);
    GLD16(Vg1, &Vs[0][ko1]);

    int buf = 0;
    for (int kt = 0; kt < SEQ; kt += 64, buf ^= 1) {
        __syncthreads();   // vmcnt(0) drain covers tile-kt loads (issued last iter)
        if (kt + 64 < SEQ) {
            GLD16(Kg0 + (size_t)(kt + 64) * 3072, &Ks[buf ^ 1][ko0]);
            GLD16(Kg1 + (size_t)(kt + 64) * 3072, &Ks[buf ^ 1][ko1]);
            GLD16(Vg0 + kt + 64, &Vs[buf ^ 1][ko0]);
            GLD16(Vg1 + kt + 64, &Vs[buf ^ 1][ko1]);
        }

        // QK^T for both q-sets
        v4f s0[4], s1[4];
#pragma unroll
        for (int nt = 0; nt < 4; nt++) {
            v8bf kf0 = *(const v8bf*)&Ks[buf][(nt * 16 + ln) * 64 + ((quad ^ sw) << 3)];
            v8bf kf1 = *(const v8bf*)&Ks[buf][(nt * 16 + ln) * 64 + (((quad + 4) ^ sw) << 3)];
            s0[nt] = (v4f){0.f, 0.f, 0.f, 0.f};
            s1[nt] = (v4f){0.f, 0.f, 0.f, 0.f};
            s0[nt] = __builtin_amdgcn_mfma_f32_16x16x32_bf16(qf[0][0], kf0, s0[nt], 0, 0, 0);
            s0[nt] = __builtin_amdgcn_mfma_f32_16x16x32_bf16(qf[0][1], kf1, s0[nt], 0, 0, 0);
            s1[nt] = __builtin_amdgcn_mfma_f32_16x16x32_bf16(qf[1][0], kf0, s1[nt], 0, 0, 0);
            s1[nt] = __builtin_amdgcn_mfma_f32_16x16x32_bf16(qf[1][1], kf1, s1[nt], 0, 0, 0);
        }

        // V fragments (shared by both q-sets)
        v8bf vf[8];
#pragma unroll
        for (int d = 0; d < 4; d++) {
            vf[d * 2]     = *(const v8bf*)&Vs[buf][(d * 16 + ln) * 64 + ((quad ^ sw) << 3)];
            vf[d * 2 + 1] = *(const v8bf*)&Vs[buf][(d * 16 + ln) * 64 + (((quad + 4) ^ sw) << 3)];
        }

        // qs0: exp2 + swizzled P store + denom
#pragma unroll
        for (int r = 0; r < 4; r++) {
            float p0 = __builtin_amdgcn_exp2f(s0[0][r]);
            float p1 = __builtin_amdgcn_exp2f(s0[1][r]);
            float p2 = __builtin_amdgcn_exp2f(s0[2][r]);
            float p3 = __builtin_amdgcn_exp2f(s0[3][r]);
            int kw = (kq + r) & 7;
            bf16_t* pr = &Pw[(quad * 4 + r) * 64 + e];
            pr[((0 + hi) ^ kw) << 3] = (bf16_t)p0;
            pr[((2 + hi) ^ kw) << 3] = (bf16_t)p1;
            pr[((4 + hi) ^ kw) << 3] = (bf16_t)p2;
            pr[((6 + hi) ^ kw) << 3] = (bf16_t)p3;
            lsum[0][r] += (p0 + p1) + (p2 + p3);
        }
        // PV qs0 (MFMAs execute async under qs1's exp2 below)
#pragma unroll
        for (int tk = 0; tk < 2; tk++) {
            v8bf pf = *(const v8bf*)&Pw[ln * 64 + (((tk * 4 + quad) ^ kr) << 3)];
#pragma unroll
            for (int d = 0; d < 4; d++)
                o[0][d] = __builtin_amdgcn_mfma_f32_16x16x32_bf16(pf, vf[tk + d * 2], o[0][d], 0, 0, 0);
        }
        // qs1: exp2 + P store (in-order DS queue: these writes follow qs0's reads)
#pragma unroll
        for (int r = 0; r < 4; r++) {
            float p0 = __builtin_amdgcn_exp2f(s1[0][r]);
            float p1 = __builtin_amdgcn_exp2f(s1[1][r]);
            float p2 = __builtin_amdgcn_exp2f(s1[2][r]);
            float p3 = __builtin_amdgcn_exp2f(s1[3][r]);
            int kw = (kq + r) & 7;
            bf16_t* pr = &Pw[(quad * 4 + r) * 64 + e];
            pr[((0 + hi) ^ kw) << 3] = (bf16_t)p0;
            pr[((2 + hi) ^ kw) << 3] = (bf16_t)p1;
            pr[((4 + hi) ^ kw) << 3] = (bf16_t)p2;
            pr[((6 + hi) ^ kw) << 3] = (bf16_t)p3;
            lsum[1][r] += (p0 + p1) + (p2 + p3);
        }
#pragma unroll
        for (int tk = 0; tk < 2; tk++) {
            v8bf pf = *(const v8bf*)&Pw[ln * 64 + (((tk * 4 + quad) ^ kr) << 3)];
#pragma unroll
            for (int d = 0; d < 4; d++)
                o[1][d] = __builtin_amdgcn_mfma_f32_16x16x32_bf16(pf, vf[tk + d * 2], o[1][d], 0, 0, 0);
        }
    }

#pragma unroll
    for (int qs = 0; qs < 2; qs++)
#pragma unroll
        for (int r = 0; r < 4; r++) {
#pragma unroll
            for (int off = 1; off < 16; off <<= 1) lsum[qs][r] += __shfl_xor(lsum[qs][r], off);
        }

#pragma unroll
    for (int qs = 0; qs < 2; qs++) {
        int rowg = b * SEQ + q0 + qs * 16;
#pragma unroll
        for (int r = 0; r < 4; r++) {
            float inv = 1.f / lsum[qs][r];
#pragma unroll
            for (int d = 0; d < 4; d++)
                attn[(size_t)(rowg + quad * 4 + r) * D_MODEL + h * 64 + d * 16 + ln] =
                    (bf16_t)(o[qs][d][r] * inv);
        }
    }
}

// ---------------------------------------------------------------- LayerNorm (one row / block)
__global__ __launch_bounds__(256) void k_layernorm(const float* __restrict__ y,
                                                   const float* __restrict__ g,
                                                   const float* __restrict__ beta,
                                                   float* __restrict__ out) {
    __shared__ float rs[4], rq[4];
    int row = blockIdx.x, t = threadIdx.x;
    int w = t >> 6, lane = t & 63;
    float4 v = ((const float4*)(y + (size_t)row * D_MODEL))[t];
    float s = v.x + v.y + v.z + v.w;
    float q = v.x * v.x + v.y * v.y + v.z * v.z + v.w * v.w;
#pragma unroll
    for (int off = 1; off < 64; off <<= 1) {
        s += __shfl_xor(s, off);
        q += __shfl_xor(q, off);
    }
    if (lane == 0) { rs[w] = s; rq[w] = q; }
    __syncthreads();
    s = rs[0] + rs[1] + rs[2] + rs[3];
    q = rq[0] + rq[1] + rq[2] + rq[3];
    float mu = s * (1.f / D_MODEL);
    float var = q * (1.f / D_MODEL) - mu * mu;
    float rstd = rsqrtf(var + 1e-5f);
    float4 gg = ((const float4*)g)[t];
    float4 bb = ((const float4*)beta)[t];
    float4 o;
    o.x = (v.x - mu) * rstd * gg.x + bb.x;
    o.y = (v.y - mu) * rstd * gg.y + bb.y;
    o.z = (v.z - mu) * rstd * gg.z + bb.z;
    o.w = (v.w - mu) * rstd * gg.w + bb.w;
    ((float4*)(out + (size_t)row * D_MODEL))[t] = o;
}

// ---------------------------------------------------------------- launch
extern "C" void kernel_launch(void* const* d_in, const int* in_sizes, int n_in,
                              void* d_out, int out_size, void* d_ws, size_t ws_size,
                              hipStream_t stream) {
    const float* batch = (const float*)d_in[0];
    const float* wq = (const float*)d_in[1];
    const float* bq = (const float*)d_in[2];
    const float* wk = (const float*)d_in[3];
    const float* bk = (const float*)d_in[4];
    const float* wv = (const float*)d_in[5];
    const float* bv = (const float*)d_in[6];
    const float* wo = (const float*)d_in[7];
    const float* bo = (const float*)d_in[8];
    const float* ln_g = (const float*)d_in[9];
    const float* ln_b = (const float*)d_in[10];
    float* out = (float*)d_out;

    char* ws = (char*)d_ws;
    size_t offXb   = 0;                                          // bf16 X (later Vt)
    size_t offWqkv = offXb + (size_t)ROWS * D_MODEL * 2;
    size_t offWo   = offWqkv + (size_t)3072 * 1024 * 2;
    size_t offBias = offWo + (size_t)1024 * 1024 * 2;
    size_t offQKV  = offBias + 3072 * 4;                         // bf16 qkv (later fp32 y)
    size_t offAttn = offQKV + (size_t)ROWS * 3072 * 2;
    size_t total   = offAttn + (size_t)ROWS * D_MODEL * 2;       // = 92,286,976
    if (ws_size < total) return;

    bf16_t* Xb   = (bf16_t*)(ws + offXb);
    bf16_t* Vt   = (bf16_t*)(ws + offXb);
    bf16_t* Wqkv = (bf16_t*)(ws + offWqkv);
    bf16_t* Wob  = (bf16_t*)(ws + offWo);
    float*  bqkv = (float*)(ws + offBias);
    bf16_t* qkv  = (bf16_t*)(ws + offQKV);
    float*  y    = (float*)(ws + offQKV);
    bf16_t* attn = (bf16_t*)(ws + offAttn);

    const float SC = 0.125f * 1.44269504088896f;  // 1/sqrt(64) * log2(e), folded into Q

    k_f32_to_bf16<<<8192, 256, 0, stream>>>(batch, Xb, 2097152);
    k_f32_to_bf16<<<1024, 256, 0, stream>>>(wq, Wqkv, 262144);
    k_f32_to_bf16<<<1024, 256, 0, stream>>>(wk, Wqkv + 1048576, 262144);
    k_f32_to_bf16<<<1024, 256, 0, stream>>>(wv, Wqkv + 2097152, 262144);
    k_f32_to_bf16<<<1024, 256, 0, stream>>>(wo, Wob, 262144);
    k_pack_bias<<<4, 256, 0, stream>>>(bq, bk, bv, bqkv);

    k_gemm_bt<<<64 * 24, 256, 0, stream>>>(Xb, Wqkv, bqkv, nullptr, qkv, nullptr,
                                           8192, 3072, 1024, 1024, SC);
    k_transpose_v<<<2048, 256, 0, stream>>>(qkv, Vt);
    k_attn<<<1024, 256, 0, stream>>>(qkv, Vt, attn);
    k_gemm_bt<<<64 * 8, 256, 0, stream>>>(attn, Wob, bo, batch, nullptr, y,
                                          8192, 1024, 1024, 0, 1.0f);
    k_layernorm<<<8192, 256, 0, stream>>>(y, ln_g, ln_b, out);
}